// Round 1
// baseline (898.737 us; speedup 1.0000x reference)
//
#include <hip/hip_runtime.h>
#include <hip/hip_bf16.h>

#define T_SEQ 4096
#define HID 2048
#define NQH 16
#define NKVH 4
#define HD 128
#define KVW (NKVH * HD)          // 512
#define KVSTRIDE 1024            // fused [k|v] projection width
#define QGW (NQH * HD * 2)       // 4096

typedef __attribute__((ext_vector_type(8))) short short8;
typedef __attribute__((ext_vector_type(4))) float f32x4;
typedef __hip_bfloat16 bf16;

__device__ inline float bf2f(bf16 v) { return __bfloat162float(v); }
__device__ inline bf16 f2bf(float v) { return __float2bfloat16(v); }

__device__ inline void storeC(float* p, float v) { *p = v; }
__device__ inline void storeC(bf16* p, float v) { *p = f2bf(v); }

// ---------------- rope tables: cos/sin[t][i], i in 0..63 ----------------
__global__ void rope_tables(const int* __restrict__ pos, const float* __restrict__ inv_freq,
                            float* __restrict__ cosT, float* __restrict__ sinT) {
    int id = blockIdx.x * 256 + threadIdx.x;       // T_SEQ*64 total
    int t = id >> 6, i = id & 63;
    float f = (float)pos[t] * inv_freq[i];
    cosT[id] = cosf(f);
    sinT[id] = sinf(f);
}

// ---------------- fp32 -> bf16 straight copy ----------------
__global__ void cvt_bf16(const float* __restrict__ in, bf16* __restrict__ out, int n) {
    int id = (blockIdx.x * 256 + threadIdx.x) * 4;
    if (id >= n) return;
    float4 v = *(const float4*)(in + id);
    bf16 tmp[4] = {f2bf(v.x), f2bf(v.y), f2bf(v.z), f2bf(v.w)};
    *(uint2*)(out + id) = *(uint2*)tmp;
}

// ---------------- fp32 [R][C] -> bf16 [C][R] transpose ----------------
__global__ void cvt_transpose(const float* __restrict__ in, bf16* __restrict__ out, int R, int C) {
    __shared__ float tile[32][33];
    int tx = threadIdx.x, ty = threadIdx.y;  // 32 x 8
    int r0 = blockIdx.y * 32, c0 = blockIdx.x * 32;
#pragma unroll
    for (int k = 0; k < 4; ++k)
        tile[ty + 8 * k][tx] = in[(long)(r0 + ty + 8 * k) * C + c0 + tx];
    __syncthreads();
#pragma unroll
    for (int k = 0; k < 4; ++k)
        out[(long)(c0 + ty + 8 * k) * R + r0 + tx] = f2bf(tile[tx][ty + 8 * k]);
}

// ---------------- GEMM: C[M][N] = A[M][K](bf16) * Bt[N][K](bf16) ----------------
// 128x128 tile, BK=32, 4 waves each computing 64x64 via 4x4 16x16x32 MFMA frags.
template <typename OutT>
__global__ __launch_bounds__(256) void gemm_bt(const bf16* __restrict__ A,
                                               const bf16* __restrict__ Bt,
                                               OutT* __restrict__ C, int M, int N, int K) {
    __shared__ __align__(16) bf16 As[128 * 32];
    __shared__ __align__(16) bf16 Bs[128 * 32];
    const int tid = threadIdx.x, lane = tid & 63, wv = tid >> 6;
    const int bm = blockIdx.y * 128, bn = blockIdx.x * 128;
    const int wm = (wv >> 1) * 64, wn = (wv & 1) * 64;
    const int lr = lane & 15, lg = lane >> 4;
    f32x4 acc[4][4] = {};
    const int srow = tid >> 2, skg = (tid & 3) * 8;
    const bf16* aP = A + (long)(bm + srow) * K + skg;
    const bf16* bP = Bt + (long)(bn + srow) * K + skg;
    for (int kt = 0; kt < K; kt += 32) {
        uint4 a0 = *(const uint4*)(aP + kt);
        uint4 a1 = *(const uint4*)(aP + (long)64 * K + kt);
        uint4 b0 = *(const uint4*)(bP + kt);
        uint4 b1 = *(const uint4*)(bP + (long)64 * K + kt);
        __syncthreads();
        *(uint4*)(As + tid * 8) = a0;
        *(uint4*)(As + tid * 8 + 2048) = a1;
        *(uint4*)(Bs + tid * 8) = b0;
        *(uint4*)(Bs + tid * 8 + 2048) = b1;
        __syncthreads();
        short8 af[4], bfv[4];
#pragma unroll
        for (int m = 0; m < 4; ++m)
            af[m] = *(const short8*)(As + (wm + m * 16 + lr) * 32 + lg * 8);
#pragma unroll
        for (int n = 0; n < 4; ++n)
            bfv[n] = *(const short8*)(Bs + (wn + n * 16 + lr) * 32 + lg * 8);
#pragma unroll
        for (int m = 0; m < 4; ++m)
#pragma unroll
            for (int n = 0; n < 4; ++n)
                acc[m][n] = __builtin_amdgcn_mfma_f32_16x16x32_bf16(af[m], bfv[n], acc[m][n], 0, 0, 0);
    }
#pragma unroll
    for (int m = 0; m < 4; ++m)
#pragma unroll
        for (int n = 0; n < 4; ++n)
#pragma unroll
            for (int j = 0; j < 4; ++j) {
                int r = bm + wm + m * 16 + lg * 4 + j;
                int c = bn + wn + n * 16 + lr;
                storeC(&C[(long)r * N + c], acc[m][n][j]);
            }
}

// ---------------- in-place per-head RMSNorm + RoPE ----------------
// one wave handles one (t, head) row of 128; lane holds d=lane and d=lane+64
__global__ __launch_bounds__(256) void norm_rope(bf16* __restrict__ buf, int rowStride,
                                                 int headStride, int hshift,
                                                 const float* __restrict__ w,
                                                 const float* __restrict__ cosT,
                                                 const float* __restrict__ sinT) {
    int row = blockIdx.x * 4 + (threadIdx.x >> 6);
    int lane = threadIdx.x & 63;
    int t = row >> hshift, h = row & ((1 << hshift) - 1);
    bf16* p = buf + (long)t * rowStride + h * headStride;
    float x1 = bf2f(p[lane]), x2 = bf2f(p[lane + 64]);
    float ss = x1 * x1 + x2 * x2;
    ss += __shfl_xor(ss, 1);
    ss += __shfl_xor(ss, 2);
    ss += __shfl_xor(ss, 4);
    ss += __shfl_xor(ss, 8);
    ss += __shfl_xor(ss, 16);
    ss += __shfl_xor(ss, 32);
    float r = rsqrtf(ss * (1.0f / 128.0f) + 1e-6f);
    float c = cosT[t * 64 + lane], s = sinT[t * 64 + lane];
    float n1 = x1 * r * w[lane], n2 = x2 * r * w[lane + 64];
    p[lane] = f2bf(n1 * c - n2 * s);
    p[lane + 64] = f2bf(n2 * c + n1 * s);
}

// ---------------- causal GQA flash attention + gate ----------------
// grid (64 qblocks, 16 heads); 4 waves, wave = 16 q rows; 32-key tiles.
__global__ __launch_bounds__(256) void attn_kernel(const bf16* __restrict__ qg,
                                                   const bf16* __restrict__ kv,
                                                   bf16* __restrict__ aout) {
    __shared__ __align__(16) bf16 Vl[32][136];
    __shared__ __align__(16) bf16 Pl[4][16][32];
    const int tid = threadIdx.x, lane = tid & 63, wv = tid >> 6;
    const int h = blockIdx.y, hk = h >> 2;
    const int q0 = blockIdx.x * 64 + wv * 16;
    const int nkt = blockIdx.x * 2 + 2;
    const int lr = lane & 15, lg = lane >> 4;
    const float scale = 0.08838834764831845f;

    // Q fragments held in registers (A-frag: row = lr, k = s*32 + lg*8 + i)
    short8 aq[4];
    {
        const bf16* qp = qg + (long)(q0 + lr) * QGW + h * (HD * 2) + lg * 8;
#pragma unroll
        for (int s = 0; s < 4; ++s) aq[s] = *(const short8*)(qp + s * 32);
    }
    float m[4], l[4];
    f32x4 acc[8];
#pragma unroll
    for (int j = 0; j < 4; ++j) { m[j] = -1e30f; l[j] = 0.f; }
#pragma unroll
    for (int n = 0; n < 8; ++n) acc[n] = (f32x4){0.f, 0.f, 0.f, 0.f};

    const int vrow = tid >> 3, vc0 = (tid & 7) * 16;
    const bf16* vP = kv + KVW + hk * HD + (long)vrow * KVSTRIDE + vc0;  // V region
    const bf16* kB = kv + hk * HD;                                     // K region

    for (int kt = 0; kt < nkt; ++kt) {
        __syncthreads();  // previous tile's LDS reads done
        // stage V[32][128] tile (natural layout, padded)
        {
            const bf16* src = vP + (long)kt * 32 * KVSTRIDE;
            uint4 v0 = *(const uint4*)(src);
            uint4 v1 = *(const uint4*)(src + 8);
            *(uint4*)&Vl[vrow][vc0] = v0;
            *(uint4*)&Vl[vrow][vc0 + 8] = v1;
        }
        // S = Q K^T over 32 keys (two 16-key halves)
        f32x4 s0 = (f32x4){0, 0, 0, 0}, s1 = (f32x4){0, 0, 0, 0};
        {
            const bf16* kp = kB + (long)(kt * 32 + lr) * KVSTRIDE + lg * 8;
#pragma unroll
            for (int s = 0; s < 4; ++s) {
                short8 b0 = *(const short8*)(kp + s * 32);
                short8 b1 = *(const short8*)(kp + 16 * KVSTRIDE + s * 32);
                s0 = __builtin_amdgcn_mfma_f32_16x16x32_bf16(aq[s], b0, s0, 0, 0, 0);
                s1 = __builtin_amdgcn_mfma_f32_16x16x32_bf16(aq[s], b1, s1, 0, 0, 0);
            }
        }
        const int key0 = kt * 32 + lr;
#pragma unroll
        for (int j = 0; j < 4; ++j) {
            const int qr = q0 + lg * 4 + j;
            float f0 = s0[j] * scale, f1 = s1[j] * scale;
            const bool msk0 = key0 > qr, msk1 = key0 + 16 > qr;
            if (msk0) f0 = -1e30f;
            if (msk1) f1 = -1e30f;
            float vmx = fmaxf(f0, f1);
            vmx = fmaxf(vmx, __shfl_xor(vmx, 1));
            vmx = fmaxf(vmx, __shfl_xor(vmx, 2));
            vmx = fmaxf(vmx, __shfl_xor(vmx, 4));
            vmx = fmaxf(vmx, __shfl_xor(vmx, 8));
            float mn = fmaxf(m[j], vmx);
            float es = __expf(m[j] - mn);
            float e0 = msk0 ? 0.f : __expf(f0 - mn);
            float e1 = msk1 ? 0.f : __expf(f1 - mn);
            float rs = e0 + e1;
            rs += __shfl_xor(rs, 1);
            rs += __shfl_xor(rs, 2);
            rs += __shfl_xor(rs, 4);
            rs += __shfl_xor(rs, 8);
            l[j] = l[j] * es + rs;
            m[j] = mn;
#pragma unroll
            for (int n = 0; n < 8; ++n) acc[n][j] *= es;
            Pl[wv][lg * 4 + j][lr] = f2bf(e0);
            Pl[wv][lg * 4 + j][lr + 16] = f2bf(e1);
        }
        __syncthreads();  // Vl + Pl visible
        // PV: A-frag = P rows; B-frag gathered from Vl
        short8 pa = *(const short8*)(&Pl[wv][lr][lg * 8]);
#pragma unroll
        for (int n = 0; n < 8; ++n) {
            short8 bv;
#pragma unroll
            for (int i = 0; i < 8; ++i)
                bv[i] = *(const short*)&Vl[lg * 8 + i][n * 16 + lr];
            acc[n] = __builtin_amdgcn_mfma_f32_16x16x32_bf16(pa, bv, acc[n], 0, 0, 0);
        }
    }
    // epilogue: normalize, gate, store
    float inv[4];
#pragma unroll
    for (int j = 0; j < 4; ++j) inv[j] = 1.f / l[j];
#pragma unroll
    for (int n = 0; n < 8; ++n)
#pragma unroll
        for (int j = 0; j < 4; ++j) {
            int t = q0 + lg * 4 + j, d = n * 16 + lr;
            float g = bf2f(qg[(long)t * QGW + h * (HD * 2) + HD + d]);
            float o = acc[n][j] * inv[j] * (1.f / (1.f + __expf(-g)));
            aout[(long)t * (NQH * HD) + h * HD + d] = f2bf(o);
        }
}

extern "C" void kernel_launch(void* const* d_in, const int* in_sizes, int n_in,
                              void* d_out, int out_size, void* d_ws, size_t ws_size,
                              hipStream_t stream) {
    const float* x = (const float*)d_in[0];
    const int* pos = (const int*)d_in[1];
    const float* inv_freq = (const float*)d_in[2];
    const float* Wq = (const float*)d_in[3];
    const float* Wk = (const float*)d_in[4];
    const float* Wv = (const float*)d_in[5];
    const float* Wo = (const float*)d_in[6];
    const float* qw = (const float*)d_in[7];
    const float* kw = (const float*)d_in[8];
    float* out = (float*)d_out;

    char* ws = (char*)d_ws;
    float* cosT = (float*)ws;               ws += (long)T_SEQ * 64 * 4;
    float* sinT = (float*)ws;               ws += (long)T_SEQ * 64 * 4;
    bf16* bx = (bf16*)ws;                   ws += (long)T_SEQ * HID * 2;
    bf16* bWq = (bf16*)ws;                  ws += (long)QGW * HID * 2;
    bf16* bKV = (bf16*)ws;                  ws += (long)KVSTRIDE * HID * 2;   // [Wk^T ; Wv^T]
    bf16* bWo = (bf16*)ws;                  ws += (long)HID * HID * 2;
    bf16* qg = (bf16*)ws;                   ws += (long)T_SEQ * QGW * 2;
    bf16* kvb = (bf16*)ws;                  ws += (long)T_SEQ * KVSTRIDE * 2;
    bf16* aout = (bf16*)ws;                 ws += (long)T_SEQ * (NQH * HD) * 2;

    rope_tables<<<T_SEQ * 64 / 256, 256, 0, stream>>>(pos, inv_freq, cosT, sinT);
    cvt_bf16<<<(T_SEQ * HID / 4 + 255) / 256, 256, 0, stream>>>(x, bx, T_SEQ * HID);
    cvt_transpose<<<dim3(QGW / 32, HID / 32), dim3(32, 8), 0, stream>>>(Wq, bWq, HID, QGW);
    cvt_transpose<<<dim3(KVW / 32, HID / 32), dim3(32, 8), 0, stream>>>(Wk, bKV, HID, KVW);
    cvt_transpose<<<dim3(KVW / 32, HID / 32), dim3(32, 8), 0, stream>>>(Wv, bKV + (long)KVW * HID, HID, KVW);
    cvt_transpose<<<dim3(HID / 32, HID / 32), dim3(32, 8), 0, stream>>>(Wo, bWo, HID, HID);

    gemm_bt<bf16><<<dim3(QGW / 128, T_SEQ / 128), 256, 0, stream>>>(bx, bWq, qg, T_SEQ, QGW, HID);
    gemm_bt<bf16><<<dim3(KVSTRIDE / 128, T_SEQ / 128), 256, 0, stream>>>(bx, bKV, kvb, T_SEQ, KVSTRIDE, HID);

    norm_rope<<<(T_SEQ * NQH) / 4, 256, 0, stream>>>(qg, QGW, HD * 2, 4, qw, cosT, sinT);
    norm_rope<<<(T_SEQ * NKVH) / 4, 256, 0, stream>>>(kvb, KVSTRIDE, HD, 2, kw, cosT, sinT);

    attn_kernel<<<dim3(T_SEQ / 64, NQH), 256, 0, stream>>>(qg, kvb, aout);

    gemm_bt<float><<<dim3(HID / 128, T_SEQ / 128), 256, 0, stream>>>(aout, bWo, out, T_SEQ, HID, NQH * HD);
}

// Round 3
// 712.400 us; speedup vs baseline: 1.2616x; 1.2616x over previous
//
#include <hip/hip_runtime.h>
#include <hip/hip_bf16.h>

#define T_SEQ 4096
#define HID 2048
#define NQH 16
#define NKVH 4
#define HD 128
#define KVW (NKVH * HD)          // 512
#define KVSTRIDE 1024            // fused [k|v] projection width
#define QGW (NQH * HD * 2)       // 4096

typedef __attribute__((ext_vector_type(8))) short short8;
typedef __attribute__((ext_vector_type(4))) float f32x4;
typedef __hip_bfloat16 bf16;

__device__ inline float bf2f(bf16 v) { return __bfloat162float(v); }
__device__ inline bf16 f2bf(float v) { return __float2bfloat16(v); }

__device__ inline void storeC(float* p, float v) { *p = v; }
__device__ inline void storeC(bf16* p, float v) { *p = f2bf(v); }

// async global->LDS, 16B per lane; LDS dest = wave-uniform base + lane*16
__device__ inline void gload16(const void* g, void* l) {
    __builtin_amdgcn_global_load_lds(
        (const __attribute__((address_space(1))) void*)g,
        (__attribute__((address_space(3))) void*)l, 16, 0, 0);
}

// XOR-swizzled LDS addressing: physical byte = row*rowBytes + (colByte ^ ((row&7)<<4))
__device__ inline void* swzp(void* base, int row, int rowBytes, int colByte) {
    int off = row * rowBytes + colByte;
    off ^= (row & 7) << 4;
    return (char*)base + off;
}
__device__ inline const void* swzc(const void* base, int row, int rowBytes, int colByte) {
    int off = row * rowBytes + colByte;
    off ^= (row & 7) << 4;
    return (const char*)base + off;
}

// ---------------- rope tables: cos/sin[t][i], i in 0..63 ----------------
__global__ void rope_tables(const int* __restrict__ pos, const float* __restrict__ inv_freq,
                            float* __restrict__ cosT, float* __restrict__ sinT) {
    int id = blockIdx.x * 256 + threadIdx.x;       // T_SEQ*64 total
    int t = id >> 6, i = id & 63;
    float f = (float)pos[t] * inv_freq[i];
    cosT[id] = cosf(f);
    sinT[id] = sinf(f);
}

// ---------------- fp32 -> bf16 straight copy ----------------
__global__ void cvt_bf16(const float* __restrict__ in, bf16* __restrict__ out, int n) {
    int id = (blockIdx.x * 256 + threadIdx.x) * 4;
    if (id >= n) return;
    float4 v = *(const float4*)(in + id);
    bf16 tmp[4] = {f2bf(v.x), f2bf(v.y), f2bf(v.z), f2bf(v.w)};
    *(uint2*)(out + id) = *(uint2*)tmp;
}

// ---------------- fp32 [R][C] -> bf16 [C][R] transpose ----------------
__global__ void cvt_transpose(const float* __restrict__ in, bf16* __restrict__ out, int R, int C) {
    __shared__ float tile[32][33];
    int tx = threadIdx.x, ty = threadIdx.y;  // 32 x 8
    int r0 = blockIdx.y * 32, c0 = blockIdx.x * 32;
#pragma unroll
    for (int k = 0; k < 4; ++k)
        tile[ty + 8 * k][tx] = in[(long)(r0 + ty + 8 * k) * C + c0 + tx];
    __syncthreads();
#pragma unroll
    for (int k = 0; k < 4; ++k)
        out[(long)(c0 + ty + 8 * k) * R + r0 + tx] = f2bf(tile[tx][ty + 8 * k]);
}

// ---------------- bf16 V-part transpose: kvb[t][KVW+d] -> vT[d][t] ----------------
__global__ void transpose_v(const bf16* __restrict__ kvb, bf16* __restrict__ vT) {
    __shared__ bf16 tile[32][33];
    int tx = threadIdx.x, ty = threadIdx.y;  // 32 x 8
    int d0 = blockIdx.x * 32, t0 = blockIdx.y * 32;
#pragma unroll
    for (int k = 0; k < 4; ++k)
        tile[ty + 8 * k][tx] = kvb[(long)(t0 + ty + 8 * k) * KVSTRIDE + KVW + d0 + tx];
    __syncthreads();
#pragma unroll
    for (int k = 0; k < 4; ++k)
        vT[(long)(d0 + ty + 8 * k) * T_SEQ + t0 + tx] = tile[tx][ty + 8 * k];
}

// ---------------- GEMM: C[M][N] = A[M][K](bf16) * Bt[N][K](bf16) ----------------
// 128x128 tile, BK=32, global_load_lds staging (m97 structure).
template <typename OutT>
__global__ __launch_bounds__(256) void gemm_bt(const bf16* __restrict__ A,
                                               const bf16* __restrict__ Bt,
                                               OutT* __restrict__ C, int M, int N, int K) {
    __shared__ __align__(16) bf16 As[128 * 32];
    __shared__ __align__(16) bf16 Bs[128 * 32];
    const int tid = threadIdx.x, lane = tid & 63, wv = tid >> 6;
    const int bm = blockIdx.y * 128, bn = blockIdx.x * 128;
    const int wm = (wv >> 1) * 64, wn = (wv & 1) * 64;
    const int lr = lane & 15, lg = lane >> 4;
    f32x4 acc[4][4] = {};
    const int srow = tid >> 2, skg = (tid & 3) * 8;
    const bf16* aP = A + (long)(bm + srow) * K + skg;
    const bf16* bP = Bt + (long)(bn + srow) * K + skg;
    bf16* asBase = As + wv * 512;   // lane-linear: wave writes 64*16B
    bf16* bsBase = Bs + wv * 512;
    for (int kt = 0; kt < K; kt += 32) {
        __syncthreads();  // previous tile consumed
        gload16(aP + kt, asBase);
        gload16(aP + (long)64 * K + kt, asBase + 2048);
        gload16(bP + kt, bsBase);
        gload16(bP + (long)64 * K + kt, bsBase + 2048);
        __syncthreads();  // drains vmcnt -> tile visible
        short8 af[4], bfv[4];
#pragma unroll
        for (int m = 0; m < 4; ++m)
            af[m] = *(const short8*)(As + (wm + m * 16 + lr) * 32 + lg * 8);
#pragma unroll
        for (int n = 0; n < 4; ++n)
            bfv[n] = *(const short8*)(Bs + (wn + n * 16 + lr) * 32 + lg * 8);
#pragma unroll
        for (int m = 0; m < 4; ++m)
#pragma unroll
            for (int n = 0; n < 4; ++n)
                acc[m][n] = __builtin_amdgcn_mfma_f32_16x16x32_bf16(af[m], bfv[n], acc[m][n], 0, 0, 0);
    }
#pragma unroll
    for (int m = 0; m < 4; ++m)
#pragma unroll
        for (int n = 0; n < 4; ++n)
#pragma unroll
            for (int j = 0; j < 4; ++j) {
                int r = bm + wm + m * 16 + lg * 4 + j;
                int c = bn + wn + n * 16 + lr;
                storeC(&C[(long)r * N + c], acc[m][n][j]);
            }
}

// ---------------- in-place per-head RMSNorm + RoPE ----------------
__global__ __launch_bounds__(256) void norm_rope(bf16* __restrict__ buf, int rowStride,
                                                 int headStride, int hshift,
                                                 const float* __restrict__ w,
                                                 const float* __restrict__ cosT,
                                                 const float* __restrict__ sinT) {
    int row = blockIdx.x * 4 + (threadIdx.x >> 6);
    int lane = threadIdx.x & 63;
    int t = row >> hshift, h = row & ((1 << hshift) - 1);
    bf16* p = buf + (long)t * rowStride + h * headStride;
    float x1 = bf2f(p[lane]), x2 = bf2f(p[lane + 64]);
    float ss = x1 * x1 + x2 * x2;
    ss += __shfl_xor(ss, 1);
    ss += __shfl_xor(ss, 2);
    ss += __shfl_xor(ss, 4);
    ss += __shfl_xor(ss, 8);
    ss += __shfl_xor(ss, 16);
    ss += __shfl_xor(ss, 32);
    float r = rsqrtf(ss * (1.0f / 128.0f) + 1e-6f);
    float c = cosT[t * 64 + lane], s = sinT[t * 64 + lane];
    float n1 = x1 * r * w[lane], n2 = x2 * r * w[lane + 64];
    p[lane] = f2bf(n1 * c - n2 * s);
    p[lane + 64] = f2bf(n2 * c + n1 * s);
}

// ---------------- causal GQA flash attention v2 + gate ----------------
// 1024 blocks; block = 64 q rows (4 waves x 16), 64-key tiles, K+V^T in LDS (XOR-swizzled).
__global__ __launch_bounds__(256) void attn2(const bf16* __restrict__ qg,
                                             const bf16* __restrict__ kvb,
                                             const bf16* __restrict__ vT,
                                             bf16* __restrict__ aout) {
    __shared__ __align__(16) bf16 Ks[64 * 128];   // [key][d], swizzled
    __shared__ __align__(16) bf16 Vs[128 * 64];   // [d][key], swizzled
    __shared__ __align__(16) bf16 Ps[4][16][72];  // per-wave [q][key]
    const int tid = threadIdx.x, lane = tid & 63, wv = tid >> 6;
    const int lr = lane & 15, lg = lane >> 4;
    const int flat = blockIdx.x;                  // 1024
    const int h = (flat & 7) + 8 * (flat >> 9);   // head -> XCD grouping
    const int qb = 63 - ((flat >> 3) & 63);       // heavy blocks first
    const int hk = h >> 2;
    const int q0 = qb * 64 + wv * 16;
    const int nkt = qb + 1;
    const float scale = 0.08838834764831845f;

    // Q A-frags: row=lr, k = s*32+lg*8
    short8 aq[4];
    {
        const bf16* qp = qg + (long)(q0 + lr) * QGW + h * (HD * 2) + lg * 8;
#pragma unroll
        for (int s = 0; s < 4; ++s) aq[s] = *(const short8*)(qp + s * 32);
    }
    float mrow[4], lrow[4];
    f32x4 acc[8];
#pragma unroll
    for (int j = 0; j < 4; ++j) { mrow[j] = -1e30f; lrow[j] = 0.f; }
#pragma unroll
    for (int n = 0; n < 8; ++n) acc[n] = (f32x4){0.f, 0.f, 0.f, 0.f};

    const int kr = tid >> 4, kc = (tid & 15) * 8;   // K stage: 16 rows x 128 d per pass
    const int vr = tid >> 3, vc = (tid & 7) * 8;    // V stage: 32 rows x 64 keys per pass
    const bf16* kSrc = kvb + hk * HD + (long)kr * KVSTRIDE + kc;
    const bf16* vSrc = vT + (long)(hk * HD + vr) * T_SEQ + vc;

    for (int kt = 0; kt < nkt; ++kt) {
        const int key00 = kt * 64;
        // prefetch tile to regs (in flight across the barrier)
        uint4 kreg[4], vreg[4];
#pragma unroll
        for (int i = 0; i < 4; ++i)
            kreg[i] = *(const uint4*)(kSrc + (long)(key00 + 16 * i) * KVSTRIDE);
#pragma unroll
        for (int i = 0; i < 4; ++i)
            vreg[i] = *(const uint4*)(vSrc + (long)(32 * i) * T_SEQ + key00);
        __syncthreads();  // previous tile consumed
#pragma unroll
        for (int i = 0; i < 4; ++i)
            *(uint4*)swzp(Ks, kr + 16 * i, 256, kc * 2) = kreg[i];
#pragma unroll
        for (int i = 0; i < 4; ++i)
            *(uint4*)swzp(Vs, vr + 32 * i, 128, vc * 2) = vreg[i];
        __syncthreads();

        // S = Q K^T (4 half-tiles of 16 keys)
        f32x4 sc4[4];
#pragma unroll
        for (int hf = 0; hf < 4; ++hf) sc4[hf] = (f32x4){0.f, 0.f, 0.f, 0.f};
#pragma unroll
        for (int hf = 0; hf < 4; ++hf) {
#pragma unroll
            for (int s = 0; s < 4; ++s) {
                short8 bk = *(const short8*)swzc(Ks, hf * 16 + lr, 256, s * 64 + lg * 16);
                sc4[hf] = __builtin_amdgcn_mfma_f32_16x16x32_bf16(aq[s], bk, sc4[hf], 0, 0, 0);
            }
        }

        // online softmax with defer-max (T13)
        const bool diag = (kt == nkt - 1);
        float es[4];
        bool need = false;
#pragma unroll
        for (int j = 0; j < 4; ++j) {
            const int qr = q0 + lg * 4 + j;
            float f0 = sc4[0][j] * scale, f1 = sc4[1][j] * scale;
            float f2 = sc4[2][j] * scale, f3 = sc4[3][j] * scale;
            if (diag) {
                if (key00 + lr > qr) f0 = -1e30f;
                if (key00 + 16 + lr > qr) f1 = -1e30f;
                if (key00 + 32 + lr > qr) f2 = -1e30f;
                if (key00 + 48 + lr > qr) f3 = -1e30f;
            }
            float vmx = fmaxf(fmaxf(f0, f1), fmaxf(f2, f3));
            vmx = fmaxf(vmx, __shfl_xor(vmx, 1));
            vmx = fmaxf(vmx, __shfl_xor(vmx, 2));
            vmx = fmaxf(vmx, __shfl_xor(vmx, 4));
            vmx = fmaxf(vmx, __shfl_xor(vmx, 8));
            float mo = mrow[j], mn, e;
            if (vmx <= mo + 8.f) { mn = mo; e = 1.f; }
            else { mn = vmx; e = __expf(mo - vmx); need = true; }
            float e0 = __expf(f0 - mn), e1 = __expf(f1 - mn);
            float e2 = __expf(f2 - mn), e3 = __expf(f3 - mn);
            float rs = (e0 + e1) + (e2 + e3);
            rs += __shfl_xor(rs, 1);
            rs += __shfl_xor(rs, 2);
            rs += __shfl_xor(rs, 4);
            rs += __shfl_xor(rs, 8);
            lrow[j] = lrow[j] * e + rs;
            mrow[j] = mn;
            es[j] = e;
            bf16* pp = &Ps[wv][lg * 4 + j][lr];
            pp[0] = f2bf(e0);
            pp[16] = f2bf(e1);
            pp[32] = f2bf(e2);
            pp[48] = f2bf(e3);
        }
        if (__any(need)) {
#pragma unroll
            for (int n = 0; n < 8; ++n)
#pragma unroll
                for (int j = 0; j < 4; ++j) acc[n][j] *= es[j];
        }

        // PV: A = P rows (LDS, per-wave), B = V^T rows (swizzled short8)
        short8 pa0 = *(const short8*)(&Ps[wv][lr][lg * 8]);
        short8 pa1 = *(const short8*)(&Ps[wv][lr][32 + lg * 8]);
#pragma unroll
        for (int n = 0; n < 8; ++n) {
            short8 v0 = *(const short8*)swzc(Vs, n * 16 + lr, 128, lg * 16);
            short8 v1 = *(const short8*)swzc(Vs, n * 16 + lr, 128, 64 + lg * 16);
            acc[n] = __builtin_amdgcn_mfma_f32_16x16x32_bf16(pa0, v0, acc[n], 0, 0, 0);
            acc[n] = __builtin_amdgcn_mfma_f32_16x16x32_bf16(pa1, v1, acc[n], 0, 0, 0);
        }
    }

    // epilogue: normalize, gate, store
    float inv[4];
#pragma unroll
    for (int j = 0; j < 4; ++j) inv[j] = 1.f / lrow[j];
#pragma unroll
    for (int n = 0; n < 8; ++n)
#pragma unroll
        for (int j = 0; j < 4; ++j) {
            int t = q0 + lg * 4 + j, d = n * 16 + lr;
            float g = bf2f(qg[(long)t * QGW + h * (HD * 2) + HD + d]);
            float o = acc[n][j] * inv[j] * (1.f / (1.f + __expf(-g)));
            aout[(long)t * (NQH * HD) + h * HD + d] = f2bf(o);
        }
}

extern "C" void kernel_launch(void* const* d_in, const int* in_sizes, int n_in,
                              void* d_out, int out_size, void* d_ws, size_t ws_size,
                              hipStream_t stream) {
    const float* x = (const float*)d_in[0];
    const int* pos = (const int*)d_in[1];
    const float* inv_freq = (const float*)d_in[2];
    const float* Wq = (const float*)d_in[3];
    const float* Wk = (const float*)d_in[4];
    const float* Wv = (const float*)d_in[5];
    const float* Wo = (const float*)d_in[6];
    const float* qw = (const float*)d_in[7];
    const float* kw = (const float*)d_in[8];
    float* out = (float*)d_out;

    char* ws = (char*)d_ws;
    float* cosT = (float*)ws;               ws += (long)T_SEQ * 64 * 4;
    float* sinT = (float*)ws;               ws += (long)T_SEQ * 64 * 4;
    bf16* bx = (bf16*)ws;                   ws += (long)T_SEQ * HID * 2;
    bf16* bWq = (bf16*)ws;                  ws += (long)QGW * HID * 2;
    bf16* bKV = (bf16*)ws;                  ws += (long)KVSTRIDE * HID * 2;   // [Wk^T ; Wv^T]
    bf16* bWo = (bf16*)ws;                  ws += (long)HID * HID * 2;
    bf16* qg = (bf16*)ws;                   ws += (long)T_SEQ * QGW * 2;
    bf16* kvb = (bf16*)ws;                  ws += (long)T_SEQ * KVSTRIDE * 2;
    bf16* aout = (bf16*)ws;                 ws += (long)T_SEQ * (NQH * HD) * 2;
    bf16* vT = (bf16*)bWq;  // alias: bWq consumed by qg GEMM before transpose_v runs

    rope_tables<<<T_SEQ * 64 / 256, 256, 0, stream>>>(pos, inv_freq, cosT, sinT);
    cvt_bf16<<<(T_SEQ * HID / 4 + 255) / 256, 256, 0, stream>>>(x, bx, T_SEQ * HID);
    cvt_transpose<<<dim3(QGW / 32, HID / 32), dim3(32, 8), 0, stream>>>(Wq, bWq, HID, QGW);
    cvt_transpose<<<dim3(KVW / 32, HID / 32), dim3(32, 8), 0, stream>>>(Wk, bKV, HID, KVW);
    cvt_transpose<<<dim3(KVW / 32, HID / 32), dim3(32, 8), 0, stream>>>(Wv, bKV + (long)KVW * HID, HID, KVW);
    cvt_transpose<<<dim3(HID / 32, HID / 32), dim3(32, 8), 0, stream>>>(Wo, bWo, HID, HID);

    gemm_bt<bf16><<<dim3(QGW / 128, T_SEQ / 128), 256, 0, stream>>>(bx, bWq, qg, T_SEQ, QGW, HID);
    gemm_bt<bf16><<<dim3(KVSTRIDE / 128, T_SEQ / 128), 256, 0, stream>>>(bx, bKV, kvb, T_SEQ, KVSTRIDE, HID);

    transpose_v<<<dim3(KVW / 32, T_SEQ / 32), dim3(32, 8), 0, stream>>>(kvb, vT);
    norm_rope<<<(T_SEQ * NQH) / 4, 256, 0, stream>>>(qg, QGW, HD * 2, 4, qw, cosT, sinT);
    norm_rope<<<(T_SEQ * NKVH) / 4, 256, 0, stream>>>(kvb, KVSTRIDE, HD, 2, kw, cosT, sinT);

    attn2<<<dim3(1024), 256, 0, stream>>>(qg, kvb, vT, aout);

    gemm_bt<float><<<dim3(HID / 128, T_SEQ / 128), 256, 0, stream>>>(aout, bWo, out, T_SEQ, HID, NQH * HD);
}

// Round 4
// 575.870 us; speedup vs baseline: 1.5607x; 1.2371x over previous
//
#include <hip/hip_runtime.h>
#include <hip/hip_bf16.h>

#define T_SEQ 4096
#define HID 2048
#define NQH 16
#define NKVH 4
#define HD 128
#define KVW (NKVH * HD)          // 512
#define KVSTRIDE 1024            // fused [k|v] projection width
#define QGW (NQH * HD * 2)       // 4096

typedef __attribute__((ext_vector_type(8))) short short8;
typedef __attribute__((ext_vector_type(4))) float f32x4;
typedef __hip_bfloat16 bf16;

__device__ inline float bf2f(bf16 v) { return __bfloat162float(v); }
__device__ inline bf16 f2bf(float v) { return __float2bfloat16(v); }

__device__ inline void storeC(float* p, float v) { *p = v; }
__device__ inline void storeC(bf16* p, float v) { *p = f2bf(v); }

// async global->LDS, 16B per lane; LDS dest = wave-uniform base + lane*16
__device__ inline void gload16(const void* g, void* l) {
    __builtin_amdgcn_global_load_lds(
        (const __attribute__((address_space(1))) void*)g,
        (__attribute__((address_space(3))) void*)l, 16, 0, 0);
}

// ---------------- rope tables: cos/sin[t][i], i in 0..63 ----------------
__global__ void rope_tables(const int* __restrict__ pos, const float* __restrict__ inv_freq,
                            float* __restrict__ cosT, float* __restrict__ sinT) {
    int id = blockIdx.x * 256 + threadIdx.x;       // T_SEQ*64 total
    int t = id >> 6, i = id & 63;
    float f = (float)pos[t] * inv_freq[i];
    cosT[id] = cosf(f);
    sinT[id] = sinf(f);
}

// ---------------- fp32 -> bf16 straight copy ----------------
__global__ void cvt_bf16(const float* __restrict__ in, bf16* __restrict__ out, int n) {
    int id = (blockIdx.x * 256 + threadIdx.x) * 4;
    if (id >= n) return;
    float4 v = *(const float4*)(in + id);
    bf16 tmp[4] = {f2bf(v.x), f2bf(v.y), f2bf(v.z), f2bf(v.w)};
    *(uint2*)(out + id) = *(uint2*)tmp;
}

// ---------------- fp32 [R][C] -> bf16 [C][R] transpose ----------------
__global__ void cvt_transpose(const float* __restrict__ in, bf16* __restrict__ out, int R, int C) {
    __shared__ float tile[32][33];
    int tx = threadIdx.x, ty = threadIdx.y;  // 32 x 8
    int r0 = blockIdx.y * 32, c0 = blockIdx.x * 32;
#pragma unroll
    for (int k = 0; k < 4; ++k)
        tile[ty + 8 * k][tx] = in[(long)(r0 + ty + 8 * k) * C + c0 + tx];
    __syncthreads();
#pragma unroll
    for (int k = 0; k < 4; ++k)
        out[(long)(c0 + ty + 8 * k) * R + r0 + tx] = f2bf(tile[tx][ty + 8 * k]);
}

// ---------------- bf16 V-part transpose: kvb[t][KVW+d] -> vT[d][t] ----------------
__global__ void transpose_v(const bf16* __restrict__ kvb, bf16* __restrict__ vT) {
    __shared__ bf16 tile[32][33];
    int tx = threadIdx.x, ty = threadIdx.y;  // 32 x 8
    int d0 = blockIdx.x * 32, t0 = blockIdx.y * 32;
#pragma unroll
    for (int k = 0; k < 4; ++k)
        tile[ty + 8 * k][tx] = kvb[(long)(t0 + ty + 8 * k) * KVSTRIDE + KVW + d0 + tx];
    __syncthreads();
#pragma unroll
    for (int k = 0; k < 4; ++k)
        vT[(long)(d0 + ty + 8 * k) * T_SEQ + t0 + tx] = tile[tx][ty + 8 * k];
}

// ---------------- GEMM: C[M][N] = A[M][K](bf16) * Bt[N][K](bf16) ----------------
// 128x128 tile, BK=32, global_load_lds staging (m97 structure).
template <typename OutT>
__global__ __launch_bounds__(256) void gemm_bt(const bf16* __restrict__ A,
                                               const bf16* __restrict__ Bt,
                                               OutT* __restrict__ C, int M, int N, int K) {
    __shared__ __align__(16) bf16 As[128 * 32];
    __shared__ __align__(16) bf16 Bs[128 * 32];
    const int tid = threadIdx.x, lane = tid & 63, wv = tid >> 6;
    const int bm = blockIdx.y * 128, bn = blockIdx.x * 128;
    const int wm = (wv >> 1) * 64, wn = (wv & 1) * 64;
    const int lr = lane & 15, lg = lane >> 4;
    f32x4 acc[4][4] = {};
    const int srow = tid >> 2, skg = (tid & 3) * 8;
    const bf16* aP = A + (long)(bm + srow) * K + skg;
    const bf16* bP = Bt + (long)(bn + srow) * K + skg;
    bf16* asBase = As + wv * 512;   // lane-linear: wave writes 64*16B
    bf16* bsBase = Bs + wv * 512;
    for (int kt = 0; kt < K; kt += 32) {
        __syncthreads();  // previous tile consumed
        gload16(aP + kt, asBase);
        gload16(aP + (long)64 * K + kt, asBase + 2048);
        gload16(bP + kt, bsBase);
        gload16(bP + (long)64 * K + kt, bsBase + 2048);
        __syncthreads();  // drains vmcnt -> tile visible
        short8 af[4], bfv[4];
#pragma unroll
        for (int m = 0; m < 4; ++m)
            af[m] = *(const short8*)(As + (wm + m * 16 + lr) * 32 + lg * 8);
#pragma unroll
        for (int n = 0; n < 4; ++n)
            bfv[n] = *(const short8*)(Bs + (wn + n * 16 + lr) * 32 + lg * 8);
#pragma unroll
        for (int m = 0; m < 4; ++m)
#pragma unroll
            for (int n = 0; n < 4; ++n)
                acc[m][n] = __builtin_amdgcn_mfma_f32_16x16x32_bf16(af[m], bfv[n], acc[m][n], 0, 0, 0);
    }
#pragma unroll
    for (int m = 0; m < 4; ++m)
#pragma unroll
        for (int n = 0; n < 4; ++n)
#pragma unroll
            for (int j = 0; j < 4; ++j) {
                int r = bm + wm + m * 16 + lg * 4 + j;
                int c = bn + wn + n * 16 + lr;
                storeC(&C[(long)r * N + c], acc[m][n][j]);
            }
}

// ---------------- in-place per-head RMSNorm + RoPE ----------------
__global__ __launch_bounds__(256) void norm_rope(bf16* __restrict__ buf, int rowStride,
                                                 int headStride, int hshift,
                                                 const float* __restrict__ w,
                                                 const float* __restrict__ cosT,
                                                 const float* __restrict__ sinT) {
    int row = blockIdx.x * 4 + (threadIdx.x >> 6);
    int lane = threadIdx.x & 63;
    int t = row >> hshift, h = row & ((1 << hshift) - 1);
    bf16* p = buf + (long)t * rowStride + h * headStride;
    float x1 = bf2f(p[lane]), x2 = bf2f(p[lane + 64]);
    float ss = x1 * x1 + x2 * x2;
    ss += __shfl_xor(ss, 1);
    ss += __shfl_xor(ss, 2);
    ss += __shfl_xor(ss, 4);
    ss += __shfl_xor(ss, 8);
    ss += __shfl_xor(ss, 16);
    ss += __shfl_xor(ss, 32);
    float r = rsqrtf(ss * (1.0f / 128.0f) + 1e-6f);
    float c = cosT[t * 64 + lane], s = sinT[t * 64 + lane];
    float n1 = x1 * r * w[lane], n2 = x2 * r * w[lane + 64];
    p[lane] = f2bf(n1 * c - n2 * s);
    p[lane + 64] = f2bf(n2 * c + n1 * s);
}

// ---------------- causal GQA flash attention v3 (pipelined) + gate ----------------
// 1024 blocks; block = 64 q rows (4 waves x 16), 64-key tiles.
// Single LDS buffer + one-tile-ahead register prefetch (T14): loads for tile
// kt+2 are issued at the end of iteration kt and consumed (ds_write) at the
// end of iteration kt+1 -> global latency hidden under a full compute phase.
__global__ __launch_bounds__(256) void attn3(const bf16* __restrict__ qg,
                                             const bf16* __restrict__ kvb,
                                             const bf16* __restrict__ vT,
                                             bf16* __restrict__ aout) {
    __shared__ __align__(16) bf16 Ks[64 * 128];   // [key][d], XOR-swizzled (elem ^ (row&7)<<3)
    __shared__ __align__(16) bf16 Vs[128 * 64];   // [d][key], XOR-swizzled
    __shared__ __align__(16) bf16 Ps[4][16][72];  // per-wave [q][key]
    const int tid = threadIdx.x, lane = tid & 63, wv = tid >> 6;
    const int lr = lane & 15, lg = lane >> 4;
    const int flat = blockIdx.x;                  // 1024
    const int h = (flat & 7) + 8 * (flat >> 9);   // head -> XCD grouping
    const int qb = 63 - ((flat >> 3) & 63);       // heavy blocks first
    const int hk = h >> 2;
    const int q0 = qb * 64 + wv * 16;
    const int nkt = qb + 1;
    const float scale = 0.08838834764831845f;

    // Q A-frags: row=lr, k = s*32+lg*8
    short8 aq[4];
    {
        const bf16* qp = qg + (long)(q0 + lr) * QGW + h * (HD * 2) + lg * 8;
#pragma unroll
        for (int s = 0; s < 4; ++s) aq[s] = *(const short8*)(qp + s * 32);
    }
    float mrow[4], lrow[4];
    f32x4 acc[8];
#pragma unroll
    for (int j = 0; j < 4; ++j) { mrow[j] = -1e30f; lrow[j] = 0.f; }
#pragma unroll
    for (int n = 0; n < 8; ++n) acc[n] = (f32x4){0.f, 0.f, 0.f, 0.f};

    const int kr = tid >> 4, kc = (tid & 15) * 8;   // K stage: 16 rows x 128 d per pass
    const int vr = tid >> 3, vc = (tid & 7) * 8;    // V stage: 32 rows x 64 keys per pass
    const bf16* kSrc = kvb + hk * HD + (long)kr * KVSTRIDE + kc;
    const bf16* vSrc = vT + (long)(hk * HD + vr) * T_SEQ + vc;
    // swizzled element-index LDS write slots (row&7 invariant under +16/+32)
    int ksw[4], vsw[4];
#pragma unroll
    for (int i = 0; i < 4; ++i) ksw[i] = (((kr + 16 * i) << 7) + kc) ^ ((kr & 7) << 3);
#pragma unroll
    for (int i = 0; i < 4; ++i) vsw[i] = (((vr + 32 * i) << 6) + vc) ^ ((vr & 7) << 3);

    uint4 kreg[4], vreg[4];
    // ---- prologue: stage tile 0, prefetch tile 1 ----
#pragma unroll
    for (int i = 0; i < 4; ++i) kreg[i] = *(const uint4*)(kSrc + (long)(16 * i) * KVSTRIDE);
#pragma unroll
    for (int i = 0; i < 4; ++i) vreg[i] = *(const uint4*)(vSrc + (long)(32 * i) * T_SEQ);
#pragma unroll
    for (int i = 0; i < 4; ++i) *(uint4*)(Ks + ksw[i]) = kreg[i];
#pragma unroll
    for (int i = 0; i < 4; ++i) *(uint4*)(Vs + vsw[i]) = vreg[i];
    if (nkt > 1) {
#pragma unroll
        for (int i = 0; i < 4; ++i) kreg[i] = *(const uint4*)(kSrc + (long)(64 + 16 * i) * KVSTRIDE);
#pragma unroll
        for (int i = 0; i < 4; ++i) vreg[i] = *(const uint4*)(vSrc + (long)(32 * i) * T_SEQ + 64);
    }
    __syncthreads();

    for (int kt = 0; kt < nkt; ++kt) {
        const int key00 = kt * 64;

        // S = Q K^T (4 half-tiles of 16 keys)
        f32x4 sc4[4];
#pragma unroll
        for (int hf = 0; hf < 4; ++hf) sc4[hf] = (f32x4){0.f, 0.f, 0.f, 0.f};
#pragma unroll
        for (int hf = 0; hf < 4; ++hf) {
#pragma unroll
            for (int s = 0; s < 4; ++s) {
                int ki = (((hf * 16 + lr) << 7) + s * 32 + lg * 8) ^ ((lr & 7) << 3);
                short8 bk = *(const short8*)(Ks + ki);
                sc4[hf] = __builtin_amdgcn_mfma_f32_16x16x32_bf16(aq[s], bk, sc4[hf], 0, 0, 0);
            }
        }

        // online softmax with defer-max (T13)
        const bool diag = (kt == nkt - 1);
        float es[4];
        bool need = false;
#pragma unroll
        for (int j = 0; j < 4; ++j) {
            const int qr = q0 + lg * 4 + j;
            float f0 = sc4[0][j] * scale, f1 = sc4[1][j] * scale;
            float f2 = sc4[2][j] * scale, f3 = sc4[3][j] * scale;
            if (diag) {
                if (key00 + lr > qr) f0 = -1e30f;
                if (key00 + 16 + lr > qr) f1 = -1e30f;
                if (key00 + 32 + lr > qr) f2 = -1e30f;
                if (key00 + 48 + lr > qr) f3 = -1e30f;
            }
            float vmx = fmaxf(fmaxf(f0, f1), fmaxf(f2, f3));
            vmx = fmaxf(vmx, __shfl_xor(vmx, 1));
            vmx = fmaxf(vmx, __shfl_xor(vmx, 2));
            vmx = fmaxf(vmx, __shfl_xor(vmx, 4));
            vmx = fmaxf(vmx, __shfl_xor(vmx, 8));
            float mo = mrow[j], mn, e;
            if (vmx <= mo + 8.f) { mn = mo; e = 1.f; }
            else { mn = vmx; e = __expf(mo - vmx); need = true; }
            float e0 = __expf(f0 - mn), e1 = __expf(f1 - mn);
            float e2 = __expf(f2 - mn), e3 = __expf(f3 - mn);
            float rs = (e0 + e1) + (e2 + e3);
            rs += __shfl_xor(rs, 1);
            rs += __shfl_xor(rs, 2);
            rs += __shfl_xor(rs, 4);
            rs += __shfl_xor(rs, 8);
            lrow[j] = lrow[j] * e + rs;
            mrow[j] = mn;
            es[j] = e;
            bf16* pp = &Ps[wv][lg * 4 + j][lr];
            pp[0] = f2bf(e0);
            pp[16] = f2bf(e1);
            pp[32] = f2bf(e2);
            pp[48] = f2bf(e3);
        }
        if (__any(need)) {
#pragma unroll
            for (int n = 0; n < 8; ++n)
#pragma unroll
                for (int j = 0; j < 4; ++j) acc[n][j] *= es[j];
        }

        // PV: A = P rows (per-wave LDS), B = V^T rows (swizzled short8)
        short8 pa0 = *(const short8*)(&Ps[wv][lr][lg * 8]);
        short8 pa1 = *(const short8*)(&Ps[wv][lr][32 + lg * 8]);
#pragma unroll
        for (int n = 0; n < 8; ++n) {
            int vi0 = (((n * 16 + lr) << 6) + lg * 8) ^ ((lr & 7) << 3);
            int vi1 = (((n * 16 + lr) << 6) + 32 + lg * 8) ^ ((lr & 7) << 3);
            short8 v0 = *(const short8*)(Vs + vi0);
            short8 v1 = *(const short8*)(Vs + vi1);
            acc[n] = __builtin_amdgcn_mfma_f32_16x16x32_bf16(pa0, v0, acc[n], 0, 0, 0);
            acc[n] = __builtin_amdgcn_mfma_f32_16x16x32_bf16(pa1, v1, acc[n], 0, 0, 0);
        }

        // ---- restage: write tile kt+1 (regs), issue loads for tile kt+2 ----
        if (kt + 1 < nkt) {
            __syncthreads();  // all waves done reading Ks/Vs (tile kt)
#pragma unroll
            for (int i = 0; i < 4; ++i) *(uint4*)(Ks + ksw[i]) = kreg[i];
#pragma unroll
            for (int i = 0; i < 4; ++i) *(uint4*)(Vs + vsw[i]) = vreg[i];
            if (kt + 2 < nkt) {
                const int key2 = (kt + 2) * 64;
#pragma unroll
                for (int i = 0; i < 4; ++i)
                    kreg[i] = *(const uint4*)(kSrc + (long)(key2 + 16 * i) * KVSTRIDE);
#pragma unroll
                for (int i = 0; i < 4; ++i)
                    vreg[i] = *(const uint4*)(vSrc + (long)(32 * i) * T_SEQ + key2);
            }
            __syncthreads();  // tile kt+1 visible
        }
    }

    // epilogue: normalize, gate, store
    float inv[4];
#pragma unroll
    for (int j = 0; j < 4; ++j) inv[j] = 1.f / lrow[j];
#pragma unroll
    for (int n = 0; n < 8; ++n)
#pragma unroll
        for (int j = 0; j < 4; ++j) {
            int t = q0 + lg * 4 + j, d = n * 16 + lr;
            float g = bf2f(qg[(long)t * QGW + h * (HD * 2) + HD + d]);
            float o = acc[n][j] * inv[j] * (1.f / (1.f + __expf(-g)));
            aout[(long)t * (NQH * HD) + h * HD + d] = f2bf(o);
        }
}

extern "C" void kernel_launch(void* const* d_in, const int* in_sizes, int n_in,
                              void* d_out, int out_size, void* d_ws, size_t ws_size,
                              hipStream_t stream) {
    const float* x = (const float*)d_in[0];
    const int* pos = (const int*)d_in[1];
    const float* inv_freq = (const float*)d_in[2];
    const float* Wq = (const float*)d_in[3];
    const float* Wk = (const float*)d_in[4];
    const float* Wv = (const float*)d_in[5];
    const float* Wo = (const float*)d_in[6];
    const float* qw = (const float*)d_in[7];
    const float* kw = (const float*)d_in[8];
    float* out = (float*)d_out;

    char* ws = (char*)d_ws;
    float* cosT = (float*)ws;               ws += (long)T_SEQ * 64 * 4;
    float* sinT = (float*)ws;               ws += (long)T_SEQ * 64 * 4;
    bf16* bx = (bf16*)ws;                   ws += (long)T_SEQ * HID * 2;
    bf16* bWq = (bf16*)ws;                  ws += (long)QGW * HID * 2;
    bf16* bKV = (bf16*)ws;                  ws += (long)KVSTRIDE * HID * 2;   // [Wk^T ; Wv^T]
    bf16* bWo = (bf16*)ws;                  ws += (long)HID * HID * 2;
    bf16* qg = (bf16*)ws;                   ws += (long)T_SEQ * QGW * 2;
    bf16* kvb = (bf16*)ws;                  ws += (long)T_SEQ * KVSTRIDE * 2;
    bf16* aout = (bf16*)ws;                 ws += (long)T_SEQ * (NQH * HD) * 2;
    bf16* vT = (bf16*)bWq;  // alias: bWq consumed by qg GEMM before transpose_v runs

    rope_tables<<<T_SEQ * 64 / 256, 256, 0, stream>>>(pos, inv_freq, cosT, sinT);
    cvt_bf16<<<(T_SEQ * HID / 4 + 255) / 256, 256, 0, stream>>>(x, bx, T_SEQ * HID);
    cvt_transpose<<<dim3(QGW / 32, HID / 32), dim3(32, 8), 0, stream>>>(Wq, bWq, HID, QGW);
    cvt_transpose<<<dim3(KVW / 32, HID / 32), dim3(32, 8), 0, stream>>>(Wk, bKV, HID, KVW);
    cvt_transpose<<<dim3(KVW / 32, HID / 32), dim3(32, 8), 0, stream>>>(Wv, bKV + (long)KVW * HID, HID, KVW);
    cvt_transpose<<<dim3(HID / 32, HID / 32), dim3(32, 8), 0, stream>>>(Wo, bWo, HID, HID);

    gemm_bt<bf16><<<dim3(QGW / 128, T_SEQ / 128), 256, 0, stream>>>(bx, bWq, qg, T_SEQ, QGW, HID);
    gemm_bt<bf16><<<dim3(KVSTRIDE / 128, T_SEQ / 128), 256, 0, stream>>>(bx, bKV, kvb, T_SEQ, KVSTRIDE, HID);

    transpose_v<<<dim3(KVW / 32, T_SEQ / 32), dim3(32, 8), 0, stream>>>(kvb, vT);
    norm_rope<<<(T_SEQ * NQH) / 4, 256, 0, stream>>>(qg, QGW, HD * 2, 4, qw, cosT, sinT);
    norm_rope<<<(T_SEQ * NKVH) / 4, 256, 0, stream>>>(kvb, KVSTRIDE, HD, 2, kw, cosT, sinT);

    attn3<<<dim3(1024), 256, 0, stream>>>(qg, kvb, vT, aout);

    gemm_bt<float><<<dim3(HID / 128, T_SEQ / 128), 256, 0, stream>>>(aout, bWo, out, T_SEQ, HID, NQH * HD);
}

// Round 5
// 495.324 us; speedup vs baseline: 1.8144x; 1.1626x over previous
//
#include <hip/hip_runtime.h>
#include <hip/hip_bf16.h>

#define T_SEQ 4096
#define HID 2048
#define NQH 16
#define NKVH 4
#define HD 128
#define KVW (NKVH * HD)          // 512
#define KVSTRIDE 1024            // fused [k|v] projection width
#define QGW (NQH * HD * 2)       // 4096

typedef __attribute__((ext_vector_type(8))) short short8;
typedef __attribute__((ext_vector_type(4))) float f32x4;
typedef __hip_bfloat16 bf16;

__device__ inline float bf2f(bf16 v) { return __bfloat162float(v); }
__device__ inline bf16 f2bf(float v) { return __float2bfloat16(v); }

__device__ inline void storeC(float* p, float v) { *p = v; }
__device__ inline void storeC(bf16* p, float v) { *p = f2bf(v); }

// async global->LDS, 16B per lane; LDS dest = wave-uniform base + lane*16
__device__ inline void gload16(const void* g, void* l) {
    __builtin_amdgcn_global_load_lds(
        (const __attribute__((address_space(1))) void*)g,
        (__attribute__((address_space(3))) void*)l, 16, 0, 0);
}

// ---------------- rope tables: cos/sin[t][i], i in 0..63 ----------------
__global__ void rope_tables(const int* __restrict__ pos, const float* __restrict__ inv_freq,
                            float* __restrict__ cosT, float* __restrict__ sinT) {
    int id = blockIdx.x * 256 + threadIdx.x;       // T_SEQ*64 total
    int t = id >> 6, i = id & 63;
    float f = (float)pos[t] * inv_freq[i];
    cosT[id] = cosf(f);
    sinT[id] = sinf(f);
}

// ---------------- fp32 -> bf16 straight copy ----------------
__global__ void cvt_bf16(const float* __restrict__ in, bf16* __restrict__ out, int n) {
    int id = (blockIdx.x * 256 + threadIdx.x) * 4;
    if (id >= n) return;
    float4 v = *(const float4*)(in + id);
    bf16 tmp[4] = {f2bf(v.x), f2bf(v.y), f2bf(v.z), f2bf(v.w)};
    *(uint2*)(out + id) = *(uint2*)tmp;
}

// ---------------- fp32 [R][C] -> bf16 [C][R] transpose ----------------
__global__ void cvt_transpose(const float* __restrict__ in, bf16* __restrict__ out, int R, int C) {
    __shared__ float tile[32][33];
    int tx = threadIdx.x, ty = threadIdx.y;  // 32 x 8
    int r0 = blockIdx.y * 32, c0 = blockIdx.x * 32;
#pragma unroll
    for (int k = 0; k < 4; ++k)
        tile[ty + 8 * k][tx] = in[(long)(r0 + ty + 8 * k) * C + c0 + tx];
    __syncthreads();
#pragma unroll
    for (int k = 0; k < 4; ++k)
        out[(long)(c0 + ty + 8 * k) * R + r0 + tx] = f2bf(tile[tx][ty + 8 * k]);
}

// ---------------- bf16 V-part transpose: kvb[t][KVW+d] -> vT[d][t] ----------------
__global__ void transpose_v(const bf16* __restrict__ kvb, bf16* __restrict__ vT) {
    __shared__ bf16 tile[32][33];
    int tx = threadIdx.x, ty = threadIdx.y;  // 32 x 8
    int d0 = blockIdx.x * 32, t0 = blockIdx.y * 32;
#pragma unroll
    for (int k = 0; k < 4; ++k)
        tile[ty + 8 * k][tx] = kvb[(long)(t0 + ty + 8 * k) * KVSTRIDE + KVW + d0 + tx];
    __syncthreads();
#pragma unroll
    for (int k = 0; k < 4; ++k)
        vT[(long)(d0 + ty + 8 * k) * T_SEQ + t0 + tx] = tile[tx][ty + 8 * k];
}

// ---------------- GEMM: C[M][N] = A[M][K](bf16) * Bt[N][K](bf16) ----------------
// 128x128 tile, BK=32, global_load_lds staging (m97 structure).
template <typename OutT>
__global__ __launch_bounds__(256) void gemm_bt(const bf16* __restrict__ A,
                                               const bf16* __restrict__ Bt,
                                               OutT* __restrict__ C, int M, int N, int K) {
    __shared__ __align__(16) bf16 As[128 * 32];
    __shared__ __align__(16) bf16 Bs[128 * 32];
    const int tid = threadIdx.x, lane = tid & 63, wv = tid >> 6;
    const int bm = blockIdx.y * 128, bn = blockIdx.x * 128;
    const int wm = (wv >> 1) * 64, wn = (wv & 1) * 64;
    const int lr = lane & 15, lg = lane >> 4;
    f32x4 acc[4][4] = {};
    const int srow = tid >> 2, skg = (tid & 3) * 8;
    const bf16* aP = A + (long)(bm + srow) * K + skg;
    const bf16* bP = Bt + (long)(bn + srow) * K + skg;
    bf16* asBase = As + wv * 512;   // lane-linear: wave writes 64*16B
    bf16* bsBase = Bs + wv * 512;
    for (int kt = 0; kt < K; kt += 32) {
        __syncthreads();  // previous tile consumed
        gload16(aP + kt, asBase);
        gload16(aP + (long)64 * K + kt, asBase + 2048);
        gload16(bP + kt, bsBase);
        gload16(bP + (long)64 * K + kt, bsBase + 2048);
        __syncthreads();  // drains vmcnt -> tile visible
        short8 af[4], bfv[4];
#pragma unroll
        for (int m = 0; m < 4; ++m)
            af[m] = *(const short8*)(As + (wm + m * 16 + lr) * 32 + lg * 8);
#pragma unroll
        for (int n = 0; n < 4; ++n)
            bfv[n] = *(const short8*)(Bs + (wn + n * 16 + lr) * 32 + lg * 8);
#pragma unroll
        for (int m = 0; m < 4; ++m)
#pragma unroll
            for (int n = 0; n < 4; ++n)
                acc[m][n] = __builtin_amdgcn_mfma_f32_16x16x32_bf16(af[m], bfv[n], acc[m][n], 0, 0, 0);
    }
#pragma unroll
    for (int m = 0; m < 4; ++m)
#pragma unroll
        for (int n = 0; n < 4; ++n)
#pragma unroll
            for (int j = 0; j < 4; ++j) {
                int r = bm + wm + m * 16 + lg * 4 + j;
                int c = bn + wn + n * 16 + lr;
                storeC(&C[(long)r * N + c], acc[m][n][j]);
            }
}

// ---------------- in-place per-head RMSNorm + RoPE ----------------
__global__ __launch_bounds__(256) void norm_rope(bf16* __restrict__ buf, int rowStride,
                                                 int headStride, int hshift,
                                                 const float* __restrict__ w,
                                                 const float* __restrict__ cosT,
                                                 const float* __restrict__ sinT) {
    int row = blockIdx.x * 4 + (threadIdx.x >> 6);
    int lane = threadIdx.x & 63;
    int t = row >> hshift, h = row & ((1 << hshift) - 1);
    bf16* p = buf + (long)t * rowStride + h * headStride;
    float x1 = bf2f(p[lane]), x2 = bf2f(p[lane + 64]);
    float ss = x1 * x1 + x2 * x2;
    ss += __shfl_xor(ss, 1);
    ss += __shfl_xor(ss, 2);
    ss += __shfl_xor(ss, 4);
    ss += __shfl_xor(ss, 8);
    ss += __shfl_xor(ss, 16);
    ss += __shfl_xor(ss, 32);
    float r = rsqrtf(ss * (1.0f / 128.0f) + 1e-6f);
    float c = cosT[t * 64 + lane], s = sinT[t * 64 + lane];
    float n1 = x1 * r * w[lane], n2 = x2 * r * w[lane + 64];
    p[lane] = f2bf(n1 * c - n2 * s);
    p[lane + 64] = f2bf(n2 * c + n1 * s);
}

// ---------------- causal GQA flash attention v4 + gate ----------------
// 512 blocks; block = 128 q rows (4 waves x 32), 64-key tiles.
// Swapped QK^T (S^T = K·Q^T) -> lane-local softmax (2 shuffles/row-reduce).
// Pipelined K/V restage via register prefetch (T14).
__global__ __launch_bounds__(256, 2) void attn4(const bf16* __restrict__ qg,
                                                const bf16* __restrict__ kvb,
                                                const bf16* __restrict__ vT,
                                                bf16* __restrict__ aout) {
    __shared__ __align__(16) bf16 Ks[64 * 128];   // [key][d], XOR-swizzled (elem ^ (row&7)<<3)
    __shared__ __align__(16) bf16 Vs[128 * 64];   // [d][key], XOR-swizzled
    __shared__ __align__(16) bf16 Ps[4][32][72];  // per-wave [q][key] (144B rows, 16B-aligned)
    const int tid = threadIdx.x, lane = tid & 63, wv = tid >> 6;
    const int lr = lane & 15, lg = lane >> 4;
    const int flat = blockIdx.x;                  // 512
    int h, qb;
    if (flat < 256) { h = flat & 7;              qb = 31 - (flat >> 3); }   // heavy first
    else            { h = 8 + ((flat - 256) & 7); qb = (flat - 256) >> 3; } // light first
    const int hk = h >> 2;
    const int q0w = qb * 128 + wv * 32;
    const int nkt = 2 * qb + 2;
    const float scale = 0.08838834764831845f;

    // Q B-frags: col=lr -> q = q0w + sub*16 + lr, k = s*32 + lg*8
    short8 bq[2][4];
#pragma unroll
    for (int sub = 0; sub < 2; ++sub)
#pragma unroll
        for (int s = 0; s < 4; ++s)
            bq[sub][s] = *(const short8*)(qg + (long)(q0w + sub * 16 + lr) * QGW +
                                          h * (HD * 2) + s * 32 + lg * 8);

    float m2[2] = {-1e30f, -1e30f}, l2[2] = {0.f, 0.f};
    f32x4 acc[2][8];
#pragma unroll
    for (int sub = 0; sub < 2; ++sub)
#pragma unroll
        for (int n = 0; n < 8; ++n) acc[sub][n] = (f32x4){0.f, 0.f, 0.f, 0.f};

    const int kr = tid >> 4, kc = (tid & 15) * 8;   // K stage: 16 rows x 128 d per pass
    const int vr = tid >> 3, vc = (tid & 7) * 8;    // V stage: 32 rows x 64 keys per pass
    const bf16* kSrc = kvb + hk * HD + (long)kr * KVSTRIDE + kc;
    const bf16* vSrc = vT + (long)(hk * HD + vr) * T_SEQ + vc;
    int ksw[4], vsw[4];
#pragma unroll
    for (int i = 0; i < 4; ++i) ksw[i] = (((kr + 16 * i) << 7) + kc) ^ ((kr & 7) << 3);
#pragma unroll
    for (int i = 0; i < 4; ++i) vsw[i] = (((vr + 32 * i) << 6) + vc) ^ ((vr & 7) << 3);

    uint4 kreg[4], vreg[4];
    // ---- prologue: stage tile 0, prefetch tile 1 (nkt >= 2 always) ----
#pragma unroll
    for (int i = 0; i < 4; ++i) kreg[i] = *(const uint4*)(kSrc + (long)(16 * i) * KVSTRIDE);
#pragma unroll
    for (int i = 0; i < 4; ++i) vreg[i] = *(const uint4*)(vSrc + (long)(32 * i) * T_SEQ);
#pragma unroll
    for (int i = 0; i < 4; ++i) *(uint4*)(Ks + ksw[i]) = kreg[i];
#pragma unroll
    for (int i = 0; i < 4; ++i) *(uint4*)(Vs + vsw[i]) = vreg[i];
#pragma unroll
    for (int i = 0; i < 4; ++i) kreg[i] = *(const uint4*)(kSrc + (long)(64 + 16 * i) * KVSTRIDE);
#pragma unroll
    for (int i = 0; i < 4; ++i) vreg[i] = *(const uint4*)(vSrc + (long)(32 * i) * T_SEQ + 64);
    __syncthreads();

    for (int kt = 0; kt < nkt; ++kt) {
        const int key00 = kt * 64;
        if (key00 <= q0w + 31) {  // wave-uniform: skip fully-masked tiles
            // S^T = K Q^T: A = K rows (key), B = Q rows (q)
            f32x4 sc[2][4];
#pragma unroll
            for (int sub = 0; sub < 2; ++sub)
#pragma unroll
                for (int hf = 0; hf < 4; ++hf) sc[sub][hf] = (f32x4){0.f, 0.f, 0.f, 0.f};
#pragma unroll
            for (int hf = 0; hf < 4; ++hf) {
#pragma unroll
                for (int s = 0; s < 4; ++s) {
                    int ki = (((hf * 16 + lr) << 7) + s * 32 + lg * 8) ^ ((lr & 7) << 3);
                    short8 ka = *(const short8*)(Ks + ki);
                    sc[0][hf] = __builtin_amdgcn_mfma_f32_16x16x32_bf16(ka, bq[0][s], sc[0][hf], 0, 0, 0);
                    sc[1][hf] = __builtin_amdgcn_mfma_f32_16x16x32_bf16(ka, bq[1][s], sc[1][hf], 0, 0, 0);
                }
            }

            // lane-local softmax (lane owns q = q0w+sub*16+lr; 16 keys in regs)
            const bool needMask = (key00 + 63 > q0w);
            float esv[2];
            bool need = false;
#pragma unroll
            for (int sub = 0; sub < 2; ++sub) {
                const int qr = q0w + sub * 16 + lr;
                float mx = -1e30f;
#pragma unroll
                for (int hf = 0; hf < 4; ++hf)
#pragma unroll
                    for (int j = 0; j < 4; ++j) {
                        float f = sc[sub][hf][j] * scale;
                        if (needMask && (key00 + hf * 16 + lg * 4 + j > qr)) f = -1e30f;
                        sc[sub][hf][j] = f;
                        mx = fmaxf(mx, f);
                    }
                mx = fmaxf(mx, __shfl_xor(mx, 16));
                mx = fmaxf(mx, __shfl_xor(mx, 32));
                float mo = m2[sub], mn, e;
                if (mx <= mo + 8.f) { mn = mo; e = 1.f; }
                else { mn = mx; e = __expf(mo - mx); need = true; }
                float sum = 0.f;
#pragma unroll
                for (int hf = 0; hf < 4; ++hf)
#pragma unroll
                    for (int j = 0; j < 4; ++j) {
                        float p = __expf(sc[sub][hf][j] - mn);
                        sc[sub][hf][j] = p;
                        sum += p;
                    }
                sum += __shfl_xor(sum, 16);
                sum += __shfl_xor(sum, 32);
                l2[sub] = l2[sub] * e + sum;
                m2[sub] = mn;
                esv[sub] = e;
                // packed b64 P writes: Ps[wv][q][hf*16+lg*4 .. +3]
#pragma unroll
                for (int hf = 0; hf < 4; ++hf) {
                    __align__(8) bf16 t4[4];
                    t4[0] = f2bf(sc[sub][hf][0]);
                    t4[1] = f2bf(sc[sub][hf][1]);
                    t4[2] = f2bf(sc[sub][hf][2]);
                    t4[3] = f2bf(sc[sub][hf][3]);
                    *(uint2*)(&Ps[wv][sub * 16 + lr][hf * 16 + lg * 4]) = *(uint2*)t4;
                }
            }
            if (__any(need)) {
#pragma unroll
                for (int sub = 0; sub < 2; ++sub) {
                    float e0 = __shfl(esv[sub], lg * 4 + 0);
                    float e1 = __shfl(esv[sub], lg * 4 + 1);
                    float e2 = __shfl(esv[sub], lg * 4 + 2);
                    float e3 = __shfl(esv[sub], lg * 4 + 3);
#pragma unroll
                    for (int n = 0; n < 8; ++n) {
                        acc[sub][n][0] *= e0;
                        acc[sub][n][1] *= e1;
                        acc[sub][n][2] *= e2;
                        acc[sub][n][3] *= e3;
                    }
                }
            }

            // PV: A = P rows (per-wave LDS), B = V^T rows (swizzled short8)
            short8 pa[2][2];
#pragma unroll
            for (int sub = 0; sub < 2; ++sub) {
                pa[sub][0] = *(const short8*)(&Ps[wv][sub * 16 + lr][lg * 8]);
                pa[sub][1] = *(const short8*)(&Ps[wv][sub * 16 + lr][32 + lg * 8]);
            }
#pragma unroll
            for (int n = 0; n < 8; ++n) {
                int vi0 = (((n * 16 + lr) << 6) + lg * 8) ^ ((lr & 7) << 3);
                int vi1 = (((n * 16 + lr) << 6) + 32 + lg * 8) ^ ((lr & 7) << 3);
                short8 v0 = *(const short8*)(Vs + vi0);
                short8 v1 = *(const short8*)(Vs + vi1);
#pragma unroll
                for (int sub = 0; sub < 2; ++sub) {
                    acc[sub][n] = __builtin_amdgcn_mfma_f32_16x16x32_bf16(pa[sub][0], v0, acc[sub][n], 0, 0, 0);
                    acc[sub][n] = __builtin_amdgcn_mfma_f32_16x16x32_bf16(pa[sub][1], v1, acc[sub][n], 0, 0, 0);
                }
            }
        }

        // ---- restage: write tile kt+1 (regs), issue loads for tile kt+2 ----
        if (kt + 1 < nkt) {
            __syncthreads();  // all waves done reading Ks/Vs (tile kt)
#pragma unroll
            for (int i = 0; i < 4; ++i) *(uint4*)(Ks + ksw[i]) = kreg[i];
#pragma unroll
            for (int i = 0; i < 4; ++i) *(uint4*)(Vs + vsw[i]) = vreg[i];
            if (kt + 2 < nkt) {
                const int key2 = (kt + 2) * 64;
#pragma unroll
                for (int i = 0; i < 4; ++i)
                    kreg[i] = *(const uint4*)(kSrc + (long)(key2 + 16 * i) * KVSTRIDE);
#pragma unroll
                for (int i = 0; i < 4; ++i)
                    vreg[i] = *(const uint4*)(vSrc + (long)(32 * i) * T_SEQ + key2);
            }
            __syncthreads();  // tile kt+1 visible
        }
    }

    // epilogue: normalize, gate, store
    float lv[2][4];
#pragma unroll
    for (int sub = 0; sub < 2; ++sub) {
        float linv = 1.f / l2[sub];
#pragma unroll
        for (int j = 0; j < 4; ++j) lv[sub][j] = __shfl(linv, lg * 4 + j);
    }
#pragma unroll
    for (int sub = 0; sub < 2; ++sub)
#pragma unroll
        for (int n = 0; n < 8; ++n)
#pragma unroll
            for (int j = 0; j < 4; ++j) {
                int t = q0w + sub * 16 + lg * 4 + j, d = n * 16 + lr;
                float g = bf2f(qg[(long)t * QGW + h * (HD * 2) + HD + d]);
                float o = acc[sub][n][j] * lv[sub][j] * (1.f / (1.f + __expf(-g)));
                aout[(long)t * (NQH * HD) + h * HD + d] = f2bf(o);
            }
}

extern "C" void kernel_launch(void* const* d_in, const int* in_sizes, int n_in,
                              void* d_out, int out_size, void* d_ws, size_t ws_size,
                              hipStream_t stream) {
    const float* x = (const float*)d_in[0];
    const int* pos = (const int*)d_in[1];
    const float* inv_freq = (const float*)d_in[2];
    const float* Wq = (const float*)d_in[3];
    const float* Wk = (const float*)d_in[4];
    const float* Wv = (const float*)d_in[5];
    const float* Wo = (const float*)d_in[6];
    const float* qw = (const float*)d_in[7];
    const float* kw = (const float*)d_in[8];
    float* out = (float*)d_out;

    char* ws = (char*)d_ws;
    float* cosT = (float*)ws;               ws += (long)T_SEQ * 64 * 4;
    float* sinT = (float*)ws;               ws += (long)T_SEQ * 64 * 4;
    bf16* bx = (bf16*)ws;                   ws += (long)T_SEQ * HID * 2;
    bf16* bWq = (bf16*)ws;                  ws += (long)QGW * HID * 2;
    bf16* bKV = (bf16*)ws;                  ws += (long)KVSTRIDE * HID * 2;   // [Wk^T ; Wv^T]
    bf16* bWo = (bf16*)ws;                  ws += (long)HID * HID * 2;
    bf16* qg = (bf16*)ws;                   ws += (long)T_SEQ * QGW * 2;
    bf16* kvb = (bf16*)ws;                  ws += (long)T_SEQ * KVSTRIDE * 2;
    bf16* aout = (bf16*)ws;                 ws += (long)T_SEQ * (NQH * HD) * 2;
    bf16* vT = (bf16*)bWq;  // alias: bWq consumed by qg GEMM before transpose_v runs

    rope_tables<<<T_SEQ * 64 / 256, 256, 0, stream>>>(pos, inv_freq, cosT, sinT);
    cvt_bf16<<<(T_SEQ * HID / 4 + 255) / 256, 256, 0, stream>>>(x, bx, T_SEQ * HID);
    cvt_transpose<<<dim3(QGW / 32, HID / 32), dim3(32, 8), 0, stream>>>(Wq, bWq, HID, QGW);
    cvt_transpose<<<dim3(KVW / 32, HID / 32), dim3(32, 8), 0, stream>>>(Wk, bKV, HID, KVW);
    cvt_transpose<<<dim3(KVW / 32, HID / 32), dim3(32, 8), 0, stream>>>(Wv, bKV + (long)KVW * HID, HID, KVW);
    cvt_transpose<<<dim3(HID / 32, HID / 32), dim3(32, 8), 0, stream>>>(Wo, bWo, HID, HID);

    gemm_bt<bf16><<<dim3(QGW / 128, T_SEQ / 128), 256, 0, stream>>>(bx, bWq, qg, T_SEQ, QGW, HID);
    gemm_bt<bf16><<<dim3(KVSTRIDE / 128, T_SEQ / 128), 256, 0, stream>>>(bx, bKV, kvb, T_SEQ, KVSTRIDE, HID);

    transpose_v<<<dim3(KVW / 32, T_SEQ / 32), dim3(32, 8), 0, stream>>>(kvb, vT);
    norm_rope<<<(T_SEQ * NQH) / 4, 256, 0, stream>>>(qg, QGW, HD * 2, 4, qw, cosT, sinT);
    norm_rope<<<(T_SEQ * NKVH) / 4, 256, 0, stream>>>(kvb, KVSTRIDE, HD, 2, kw, cosT, sinT);

    attn4<<<dim3(512), 256, 0, stream>>>(qg, kvb, vT, aout);

    gemm_bt<float><<<dim3(HID / 128, T_SEQ / 128), 256, 0, stream>>>(aout, bWo, out, T_SEQ, HID, NQH * HD);
}